// Round 1
// baseline (888.035 us; speedup 1.0000x reference)
//
#include <hip/hip_runtime.h>
#include <hip/hip_fp16.h>

typedef _Float16 f16;
typedef _Float16 f16x8 __attribute__((ext_vector_type(8)));
typedef _Float16 f16x4 __attribute__((ext_vector_type(4)));
typedef float f32x4 __attribute__((ext_vector_type(4)));

#define SEQ 2048
#define BATCH 8

// ---------------------------------------------------------------- helpers
__device__ __forceinline__ void gl2lds16(const f16* g, f16* l) {
  // 16B-wide async global->LDS. LDS dest must be wave-uniform base; HW adds lane*16.
  __builtin_amdgcn_global_load_lds((const __attribute__((address_space(1))) void*)g,
                                   (__attribute__((address_space(3))) void*)l,
                                   16, 0, 0);
}

// ---------------------------------------------------------------- cast fp32 -> fp16
__global__ __launch_bounds__(256) void cast_kernel(const float* __restrict__ in,
                                                   f16* __restrict__ out, int n4) {
  int i = blockIdx.x * 256 + threadIdx.x;
  if (i < n4) {
    float4 v = ((const float4*)in)[i];
    f16x4 h;
    h[0] = (f16)v.x; h[1] = (f16)v.y; h[2] = (f16)v.z; h[3] = (f16)v.w;
    ((f16x4*)out)[i] = h;
  }
}

// ---------------------------------------------------------------- GEMM  C[m][n] = sum_k A[m][k] * Bt[n][k]
// A row-major [M][K], Bt row-major [N][K] (i.e. B^T), C row-major [M][N], batched via blockIdx.z.
// 128x128 tile, BK=32, 256 threads = 4 waves (2x2 of 64x64), mfma_f32_16x16x32_f16.
__global__ __launch_bounds__(256) void gemm_nt(const f16* __restrict__ A,
                                               const f16* __restrict__ Bt,
                                               float* __restrict__ C,
                                               int K, int N,
                                               long long sA, long long sB, long long sC) {
  const f16* Ab = A + blockIdx.z * sA;
  const f16* Bb = Bt + blockIdx.z * sB;
  float* Cb = C + blockIdx.z * sC;
  const int m0 = blockIdx.y * 128, n0 = blockIdx.x * 128;

  __shared__ f16 As[128][32];   // 8 KB
  __shared__ f16 Bs[128][32];   // 8 KB

  const int tid = threadIdx.x;
  const int wave = tid >> 6, lane = tid & 63;
  const int wm = (wave >> 1) << 6;       // wave row offset (0/64)
  const int wn = (wave & 1) << 6;        // wave col offset (0/64)
  const int q = lane >> 4, ml = lane & 15;

  // staging: each wave-issue covers 16 rows x 32 cols (1024B); lane l -> row l/4, col (l%4)*8
  const int lrow = lane >> 2;
  const int lcol = (lane & 3) * 8;

  f32x4 acc[4][4];
#pragma unroll
  for (int i = 0; i < 4; i++)
#pragma unroll
    for (int j = 0; j < 4; j++) acc[i][j] = (f32x4){0.f, 0.f, 0.f, 0.f};

  for (int k0 = 0; k0 < K; k0 += 32) {
#pragma unroll
    for (int i = 0; i < 2; i++) {
      const int rb = (i * 4 + wave) * 16;  // wave-uniform row base
      gl2lds16(Ab + (size_t)(m0 + rb + lrow) * K + k0 + lcol, &As[rb][0]);
      gl2lds16(Bb + (size_t)(n0 + rb + lrow) * K + k0 + lcol, &Bs[rb][0]);
    }
    __syncthreads();

    f16x8 af[4], bf[4];
#pragma unroll
    for (int i = 0; i < 4; i++) af[i] = *(const f16x8*)&As[wm + i * 16 + ml][q * 8];
#pragma unroll
    for (int j = 0; j < 4; j++) bf[j] = *(const f16x8*)&Bs[wn + j * 16 + ml][q * 8];
#pragma unroll
    for (int i = 0; i < 4; i++)
#pragma unroll
      for (int j = 0; j < 4; j++)
        acc[i][j] = __builtin_amdgcn_mfma_f32_16x16x32_f16(af[i], bf[j], acc[i][j], 0, 0, 0);
    __syncthreads();
  }

  // epilogue: C/D layout col=lane&15, row=(lane>>4)*4+reg  [m89-verified]
#pragma unroll
  for (int i = 0; i < 4; i++) {
    const int row = m0 + wm + i * 16 + q * 4;
#pragma unroll
    for (int j = 0; j < 4; j++) {
      const int col = n0 + wn + j * 16 + ml;
      float* cp = Cb + (size_t)row * N + col;
      cp[0] = acc[i][j][0];
      cp[(size_t)N] = acc[i][j][1];
      cp[2 * (size_t)N] = acc[i][j][2];
      cp[3 * (size_t)N] = acc[i][j][3];
    }
  }
}

// ---------------------------------------------------------------- per-row max & sum(exp)
__global__ __launch_bounds__(256) void row_stats(const float* __restrict__ qk,
                                                 float* __restrict__ mrow,
                                                 float* __restrict__ zrow) {
  const size_t row = blockIdx.x;  // 0 .. BATCH*SEQ-1
  const float4* p = (const float4*)(qk + row * (size_t)SEQ);
  const int t = threadIdx.x;
  float4 a = p[t];
  float4 b = p[t + 256];
  float mx = fmaxf(fmaxf(fmaxf(a.x, a.y), fmaxf(a.z, a.w)),
                   fmaxf(fmaxf(b.x, b.y), fmaxf(b.z, b.w)));
  __shared__ float red[8];
#pragma unroll
  for (int o = 32; o > 0; o >>= 1) mx = fmaxf(mx, __shfl_xor(mx, o, 64));
  if ((t & 63) == 0) red[t >> 6] = mx;
  __syncthreads();
  mx = fmaxf(fmaxf(red[0], red[1]), fmaxf(red[2], red[3]));
  float s = __expf(a.x - mx) + __expf(a.y - mx) + __expf(a.z - mx) + __expf(a.w - mx) +
            __expf(b.x - mx) + __expf(b.y - mx) + __expf(b.z - mx) + __expf(b.w - mx);
#pragma unroll
  for (int o = 32; o > 0; o >>= 1) s += __shfl_xor(s, o, 64);
  if ((t & 63) == 0) red[4 + (t >> 6)] = s;
  __syncthreads();
  if (t == 0) {
    mrow[row] = mx;
    zrow[row] = red[4] + red[5] + red[6] + red[7];
  }
}

// ---------------------------------------------------------------- P^T[k][d] = exp(qk[d][k]-m[d])/Z[d], fp16
__global__ __launch_bounds__(256) void transpose_exp(const float* __restrict__ qk,
                                                     const float* __restrict__ mrow,
                                                     const float* __restrict__ zrow,
                                                     f16* __restrict__ PT) {
  const int b = blockIdx.z;
  const int d0 = blockIdx.y * 64, k0 = blockIdx.x * 64;
  const float* qb = qk + (size_t)b * SEQ * SEQ;
  f16* pb = PT + (size_t)b * SEQ * SEQ;
  __shared__ float T[64][65];  // [k_local][d_local], pad 65 -> 2-way-max bank aliasing (free)
  const int t = threadIdx.x;
  const int rr = t >> 4, cc = (t & 15) * 4;
#pragma unroll
  for (int ch = 0; ch < 4; ch++) {
    const int r = rr + ch * 16;   // local d
    const int d = d0 + r;
    const float m = mrow[(size_t)b * SEQ + d];
    const float rz = 1.0f / zrow[(size_t)b * SEQ + d];
    float4 v = *(const float4*)(qb + (size_t)d * SEQ + k0 + cc);
    T[cc + 0][r] = __expf(v.x - m) * rz;
    T[cc + 1][r] = __expf(v.y - m) * rz;
    T[cc + 2][r] = __expf(v.z - m) * rz;
    T[cc + 3][r] = __expf(v.w - m) * rz;
  }
  __syncthreads();
  const int r2 = t >> 2, c2 = (t & 3) * 16;
  f16x8 o0, o1;
#pragma unroll
  for (int j = 0; j < 8; j++) o0[j] = (f16)T[r2][c2 + j];
#pragma unroll
  for (int j = 0; j < 8; j++) o1[j] = (f16)T[r2][c2 + 8 + j];
  f16* dst = pb + (size_t)(k0 + r2) * SEQ + d0 + c2;
  *(f16x8*)dst = o0;
  *(f16x8*)(dst + 8) = o1;
}

// ---------------------------------------------------------------- launch
extern "C" void kernel_launch(void* const* d_in, const int* in_sizes, int n_in,
                              void* d_out, int out_size, void* d_ws, size_t ws_size,
                              hipStream_t stream) {
  const float* Q = (const float*)d_in[0];
  const float* Kf = (const float*)d_in[1];
  const float* V = (const float*)d_in[2];
  // d_in[3] attn_mask: all zeros and unused by the reference.
  float* out = (float*)d_out;

  const size_t nElem = (size_t)BATCH * SEQ * SEQ;  // 33,554,432
  f16* Qh = (f16*)d_ws;
  f16* Kh = Qh + nElem;
  f16* Vh = Kh + nElem;
  f16* PT = Vh + nElem;
  float* qk = (float*)(PT + nElem);
  float* mrow = qk + nElem;
  float* zrow = mrow + (size_t)BATCH * SEQ;
  // total ws use: 4*2*nElem + 4*nElem + 2*4*BATCH*SEQ ≈ 403 MB

  const int n4 = (int)(nElem / 4);
  dim3 cgrid(n4 / 256);
  cast_kernel<<<cgrid, 256, 0, stream>>>(Q, Qh, n4);
  cast_kernel<<<cgrid, 256, 0, stream>>>(Kf, Kh, n4);
  cast_kernel<<<cgrid, 256, 0, stream>>>(V, Vh, n4);

  const long long sb = (long long)SEQ * SEQ;
  dim3 ggrid(SEQ / 128, SEQ / 128, BATCH);  // 16x16x8
  // qk[b][q][k] = sum_d Q[q][d] * K[k][d]   (NT gemm)
  gemm_nt<<<ggrid, 256, 0, stream>>>(Qh, Kh, qk, SEQ, SEQ, sb, sb, sb);

  row_stats<<<dim3(BATCH * SEQ), 256, 0, stream>>>(qk, mrow, zrow);

  transpose_exp<<<dim3(SEQ / 64, SEQ / 64, BATCH), 256, 0, stream>>>(qk, mrow, zrow, PT);

  // out[b][s][k] = sum_d V[s][d] * PT[k][d]
  gemm_nt<<<ggrid, 256, 0, stream>>>(Vh, PT, out, SEQ, SEQ, sb, sb, sb);
}

// Round 2
// 874.245 us; speedup vs baseline: 1.0158x; 1.0158x over previous
//
#include <hip/hip_runtime.h>
#include <hip/hip_fp16.h>

typedef _Float16 f16;
typedef _Float16 f16x8 __attribute__((ext_vector_type(8)));
typedef _Float16 f16x4 __attribute__((ext_vector_type(4)));
typedef float f32x4 __attribute__((ext_vector_type(4)));
typedef float f32x16 __attribute__((ext_vector_type(16)));

#define SEQ 2048
#define BATCH 8
#define NCHUNK 16  // row chunks for colstats partials

// ---------------------------------------------------------------- helpers
__device__ __forceinline__ void gl2lds16(const f16* g, f16* l) {
  // 16B-wide async global->LDS. LDS dest is wave-uniform base; HW adds lane*16.
  __builtin_amdgcn_global_load_lds((const __attribute__((address_space(1))) void*)g,
                                   (__attribute__((address_space(3))) void*)l,
                                   16, 0, 0);
}

// ---------------------------------------------------------------- cast fp32 -> fp16
__global__ __launch_bounds__(256) void cast_kernel(const float* __restrict__ in,
                                                   f16* __restrict__ out, int n4) {
  int i = blockIdx.x * 256 + threadIdx.x;
  if (i < n4) {
    float4 v = ((const float4*)in)[i];
    f16x4 h;
    h[0] = (f16)v.x; h[1] = (f16)v.y; h[2] = (f16)v.z; h[3] = (f16)v.w;
    ((f16x4*)out)[i] = h;
  }
}

// ---------------------------------------------------------------- GEMM  C[m][n] = sum_k A[m][k] * Bt[n][k]
// A row-major [M][K], Bt row-major [N][K], C row-major [M][N], batch via blockIdx.z.
// 128x128 tile, BK=32, 4 waves (2x2 of 64x64), each wave 2x2 of mfma_f32_32x32x16_f16.
__global__ __launch_bounds__(256) void gemm_nt(const f16* __restrict__ A,
                                               const f16* __restrict__ Bt,
                                               float* __restrict__ C,
                                               int K, int N,
                                               long long sA, long long sB, long long sC) {
  const f16* Ab = A + blockIdx.z * sA;
  const f16* Bb = Bt + blockIdx.z * sB;
  float* Cb = C + blockIdx.z * sC;
  const int m0 = blockIdx.y * 128, n0 = blockIdx.x * 128;

  __shared__ f16 As[128][32];   // 8 KB
  __shared__ f16 Bs[128][32];   // 8 KB

  const int tid = threadIdx.x;
  const int wave = tid >> 6, lane = tid & 63;
  const int wm = (wave >> 1) << 6;       // wave row offset (0/64)
  const int wn = (wave & 1) << 6;        // wave col offset (0/64)
  const int l31 = lane & 31, h = lane >> 5;   // mfma 32x32: row/col = l31, k-half = h

  // staging: each wave-issue covers 16 rows x 32 cols (1024B); lane l -> row l/4, col (l%4)*8
  const int lrow = lane >> 2;
  const int lcol = (lane & 3) * 8;

  f32x16 acc[2][2];
#pragma unroll
  for (int i = 0; i < 2; i++)
#pragma unroll
    for (int j = 0; j < 2; j++)
#pragma unroll
      for (int r = 0; r < 16; r++) acc[i][j][r] = 0.f;

  for (int k0 = 0; k0 < K; k0 += 32) {
#pragma unroll
    for (int i = 0; i < 2; i++) {
      const int rb = (i * 4 + wave) * 16;  // wave-uniform row base
      gl2lds16(Ab + (size_t)(m0 + rb + lrow) * K + k0 + lcol, &As[rb][0]);
      gl2lds16(Bb + (size_t)(n0 + rb + lrow) * K + k0 + lcol, &Bs[rb][0]);
    }
    __syncthreads();

#pragma unroll
    for (int s = 0; s < 2; s++) {
      f16x8 a0 = *(const f16x8*)&As[wm + l31][s * 16 + h * 8];
      f16x8 a1 = *(const f16x8*)&As[wm + 32 + l31][s * 16 + h * 8];
      f16x8 b0 = *(const f16x8*)&Bs[wn + l31][s * 16 + h * 8];
      f16x8 b1 = *(const f16x8*)&Bs[wn + 32 + l31][s * 16 + h * 8];
      acc[0][0] = __builtin_amdgcn_mfma_f32_32x32x16_f16(a0, b0, acc[0][0], 0, 0, 0);
      acc[0][1] = __builtin_amdgcn_mfma_f32_32x32x16_f16(a0, b1, acc[0][1], 0, 0, 0);
      acc[1][0] = __builtin_amdgcn_mfma_f32_32x32x16_f16(a1, b0, acc[1][0], 0, 0, 0);
      acc[1][1] = __builtin_amdgcn_mfma_f32_32x32x16_f16(a1, b1, acc[1][1], 0, 0, 0);
    }
    __syncthreads();
  }

  // epilogue: 32x32 C/D layout col=lane&31, row=(reg&3)+8*(reg>>2)+4*(lane>>5) [m74/m101]
#pragma unroll
  for (int i = 0; i < 2; i++) {
#pragma unroll
    for (int j = 0; j < 2; j++) {
      const int colb = n0 + wn + j * 32 + l31;
      const int rowb = m0 + wm + i * 32 + 4 * h;
#pragma unroll
      for (int r = 0; r < 16; r++) {
        const int row = rowb + (r & 3) + 8 * (r >> 2);
        Cb[(size_t)row * N + colb] = acc[i][j][r];
      }
    }
  }
}

// ---------------------------------------------------------------- per-column online (max, sumexp) partials
// G[k][q] per batch; stats over k (rows) for each column q. Grid: (SEQ/256, NCHUNK, BATCH).
__global__ __launch_bounds__(256) void colstats_part(const float* __restrict__ G,
                                                     float* __restrict__ pm,
                                                     float* __restrict__ ps) {
  const int b = blockIdx.z, chunk = blockIdx.y;
  const int q = blockIdx.x * 256 + threadIdx.x;
  const int rows = SEQ / NCHUNK;  // 128
  const float* p = G + (size_t)b * SEQ * SEQ + (size_t)chunk * rows * SEQ + q;
  float m = -3.0e38f, s = 0.f;
#pragma unroll 4
  for (int k = 0; k < rows; k++) {
    float x = p[(size_t)k * SEQ];
    if (x > m) { s = s * __expf(m - x) + 1.f; m = x; }
    else       { s += __expf(x - m); }
  }
  const size_t o = ((size_t)chunk * BATCH + b) * SEQ + q;
  pm[o] = m;
  ps[o] = s;
}

// ---------------------------------------------------------------- combine partials -> m, 1/Z
__global__ __launch_bounds__(256) void colstats_combine(const float* __restrict__ pm,
                                                        const float* __restrict__ ps,
                                                        float* __restrict__ mrow,
                                                        float* __restrict__ rzrow) {
  const int b = blockIdx.y;
  const int q = blockIdx.x * 256 + threadIdx.x;
  float m = -3.0e38f, s = 0.f;
#pragma unroll
  for (int c = 0; c < NCHUNK; c++) {
    const size_t o = ((size_t)c * BATCH + b) * SEQ + q;
    float mc = pm[o], sc = ps[o];
    if (mc > m) { s = s * __expf(m - mc) + sc; m = mc; }
    else        { s += sc * __expf(mc - m); }
  }
  mrow[(size_t)b * SEQ + q] = m;
  rzrow[(size_t)b * SEQ + q] = 1.f / s;
}

// ---------------------------------------------------------------- PT[k][q] = exp(G[k][q]-m[q])/Z[q], fp16
__global__ __launch_bounds__(256) void scale_kernel(const float* __restrict__ G,
                                                    const float* __restrict__ mrow,
                                                    const float* __restrict__ rzrow,
                                                    f16* __restrict__ PT) {
  const int i = blockIdx.x * 256 + threadIdx.x;   // float4 index, < 2^23
  const int b = i >> 20;                          // SEQ*SEQ/4 = 2^20 per batch
  const int cg = i & (SEQ / 4 - 1);               // column group
  float4 g = ((const float4*)G)[i];
  float4 m4 = ((const float4*)(mrow + (size_t)b * SEQ))[cg];
  float4 z4 = ((const float4*)(rzrow + (size_t)b * SEQ))[cg];
  f16x4 o;
  o[0] = (f16)(__expf(g.x - m4.x) * z4.x);
  o[1] = (f16)(__expf(g.y - m4.y) * z4.y);
  o[2] = (f16)(__expf(g.z - m4.z) * z4.z);
  o[3] = (f16)(__expf(g.w - m4.w) * z4.w);
  ((f16x4*)PT)[i] = o;
}

// ---------------------------------------------------------------- launch
extern "C" void kernel_launch(void* const* d_in, const int* in_sizes, int n_in,
                              void* d_out, int out_size, void* d_ws, size_t ws_size,
                              hipStream_t stream) {
  const float* Q = (const float*)d_in[0];
  const float* Kf = (const float*)d_in[1];
  const float* V = (const float*)d_in[2];
  // d_in[3] attn_mask: all zeros, unused by the reference.
  float* out = (float*)d_out;

  const size_t nElem = (size_t)BATCH * SEQ * SEQ;  // 33,554,432
  f16* Qh = (f16*)d_ws;
  f16* Kh = Qh + nElem;
  f16* Vh = Kh + nElem;
  f16* PT = Vh + nElem;
  float* G = (float*)(PT + nElem);                 // qk^T: G[b][k][q]
  float* mrow = G + nElem;
  float* rzrow = mrow + (size_t)BATCH * SEQ;
  // partials overlay Qh's region (Qh is dead after GEMM1; partials written after GEMM1)
  float* pm = (float*)Qh;
  float* ps = pm + (size_t)NCHUNK * BATCH * SEQ;
  // total ws use unchanged from round 1: ~403 MB

  const int n4 = (int)(nElem / 4);
  dim3 cgrid(n4 / 256);
  cast_kernel<<<cgrid, 256, 0, stream>>>(Q, Qh, n4);
  cast_kernel<<<cgrid, 256, 0, stream>>>(Kf, Kh, n4);
  cast_kernel<<<cgrid, 256, 0, stream>>>(V, Vh, n4);

  const long long sb = (long long)SEQ * SEQ;
  dim3 ggrid(SEQ / 128, SEQ / 128, BATCH);  // 16x16x8
  // G[k][q] = sum_d K[k][d] * Q[q][d]  ( = qk[q][k] transposed )
  gemm_nt<<<ggrid, 256, 0, stream>>>(Kh, Qh, G, SEQ, SEQ, sb, sb, sb);

  colstats_part<<<dim3(SEQ / 256, NCHUNK, BATCH), 256, 0, stream>>>(G, pm, ps);
  colstats_combine<<<dim3(SEQ / 256, BATCH), 256, 0, stream>>>(pm, ps, mrow, rzrow);

  scale_kernel<<<dim3(n4 / 256), 256, 0, stream>>>(G, mrow, rzrow, PT);

  // out[s][n] = sum_d V[s][d] * PT[n][d]
  gemm_nt<<<ggrid, 256, 0, stream>>>(Vh, PT, out, SEQ, SEQ, sb, sb, sb);
}